// Round 10
// baseline (87.497 us; speedup 1.0000x reference)
//
#include <hip/hip_runtime.h>

#define IN_C 32
#define HW 64
#define Q_N 36

typedef float f32x4 __attribute__((ext_vector_type(4)));
typedef short s16x8 __attribute__((ext_vector_type(8)));
typedef short s16x4 __attribute__((ext_vector_type(4)));

// workspace layout (bytes)
#define WEXP_OFF 0          // [36 q][4 mt][16 pr][8 j] bf16 = 73728 B
#define ZW_OFF   73728      // 512 B zeros (A-fragment K-padding lanes l>=16)
#define SCL_OFF  74240      // f32[36] signed scale * E
#define GX2_OFF  75776      // bf16 GI*x^2, [8][32][64][64] = 2097152 B

__device__ __forceinline__ unsigned short f2bf(float f) {
    union { float f; unsigned int u; } v; v.f = f;
    unsigned int t = v.u + 0x7FFFu + ((v.u >> 16) & 1u);   // RNE
    return (unsigned short)(t >> 16);
}

#define A_C 0.8578f
#define R_C 0.8985f
#define S_C (A_C*A_C + R_C*R_C)
#define D_C (1.f + (A_C*R_C)*(A_C*R_C))
#define C2_C (2.f*A_C*R_C)
#define E_C (S_C - D_C)
#define GI_C (1.6666666666666667f * 0.15915494309189535f)   // gain/(2*pi)

__global__ __launch_bounds__(512)
void morr_pre(const float* __restrict__ x,
              const float* __restrict__ weight,
              const float* __restrict__ mos,
              unsigned char* __restrict__ ws)
{
    const int tid = threadIdx.x;
    const int blk = blockIdx.x;
    if (blk < 512) {
        const int i = (blk * 512 + tid) * 4;
        float4 v = *(const float4*)(x + i);
        s16x4 o = {(short)f2bf(GI_C * v.x * v.x), (short)f2bf(GI_C * v.y * v.y),
                   (short)f2bf(GI_C * v.z * v.z), (short)f2bf(GI_C * v.w * v.w)};
        *(s16x4*)(ws + GX2_OFF + (size_t)i * 2) = o;
    } else {
        unsigned short* wexp = (unsigned short*)(ws + WEXP_OFF);
#pragma unroll
        for (int it = 0; it < 72; ++it) {
            const int idx = tid + 512 * it;
            const int q  = idx >> 9;
            const int mt = (idx >> 7) & 3;
            const int pr = (idx >> 3) & 15;
            const int j  = idx & 7;
            const int pk = mt * 16 + pr;
            const int p  = pk >> 3, k = pk & 7;
            wexp[idx] = f2bf(weight[p * 288 + q * 8 + ((k - j) & 7)]);
        }
        if (tid < 128) ((float*)(ws + ZW_OFF))[tid] = 0.f;
        if (tid < Q_N)
            ((float*)(ws + SCL_OFF))[tid] =
                ((tid < 18) ? mos[tid] : -mos[tid - 18]) * E_C;
    }
}

// block = quarter-row: (image b, row, 16-px tile). 4 waves, wave = mt tile.
__global__ __launch_bounds__(256, 8)
void morr_conv_kernel(const unsigned char* __restrict__ ws,
                      float* __restrict__ out)
{
    __shared__ __align__(16) unsigned short Aim[16 * 296];   // 9472 B

    const int tid = threadIdx.x;
    const int blk = blockIdx.x;
    const int b   = blk >> 8;
    const int rem = blk & 255;
    const int row = rem >> 2;
    const int w0  = (rem & 3) << 4;

    const unsigned short* gx2 = (const unsigned short*)(ws + GX2_OFF);

    // ---- stage im2col: thread (px=tid&15, g=tid>>4) owns u in [18g,18g+18) ----
    {
        const int px = tid & 15;
        const int g  = tid >> 4;        // channels 2g, 2g+1
        unsigned int wbuf[9];
#pragma unroll
        for (int cc = 0; cc < 2; ++cc) {
            const int c = 2 * g + cc;
            const unsigned short* xc = gx2 + ((b * IN_C + c) << 12);
            unsigned short e[9];
#pragma unroll
            for (int ki = 0; ki < 3; ++ki) {
                const int gh = row + ki - 1;
                const bool rok = (unsigned)gh < 64u;
#pragma unroll
                for (int kj = 0; kj < 3; ++kj) {
                    const int gw = w0 + px + kj - 1;
                    unsigned short v = 0;
                    if (rok && (unsigned)gw < 64u) v = xc[(gh << 6) + gw];
                    e[ki * 3 + kj] = v;
                }
            }
#pragma unroll
            for (int i = 0; i < 4; ++i)
                wbuf[cc * 4 + i + cc] = (unsigned)e[2*i + (cc ? 1 : 0)] |
                                        ((unsigned)e[2*i + 1 + (cc ? 1 : 0)] << 16);
            if (cc == 0) wbuf[4] = (unsigned)e[8];       // low half, patched below
            else         wbuf[4] |= ((unsigned)e[0] << 16);
        }
        // wbuf layout fix: elements u=18g..18g+17 packed pairwise:
        // cc=0: e0..e8 -> wbuf[0..3] = pairs(e0..e7), wbuf[4].lo = e8
        // cc=1: wbuf[4].hi = e0, wbuf[5..8] = pairs(e1..e8)
        unsigned int* dst = (unsigned int*)((unsigned char*)Aim + px * 592 + g * 36);
#pragma unroll
        for (int i = 0; i < 9; ++i) dst[i] = wbuf[i];
    }
    __syncthreads();

    const int wv = tid >> 6;         // wave = mt tile 0..3
    const int l  = tid & 63;
    const int ll = l & 15;
    const int lh = l >> 4;

    const unsigned short* bB = Aim + ll * 296;     // B: px = ll
    // A: lanes l<16 real weights; l>=16 zero page (kills K-slots 8..31)
    const unsigned short* aW;
    int qs;
    if (l < 16) { aW = (const unsigned short*)(ws + WEXP_OFF) + (wv * 16 + ll) * 8; qs = 512; }
    else        { aW = (const unsigned short*)(ws + ZW_OFF);                        qs = 0;   }
    const float* __restrict__ sp = (const float*)(ws + SCL_OFF);

    float acc[4] = {0.f, 0.f, 0.f, 0.f};
    const f32x4 cz = {0.f, 0.f, 0.f, 0.f};

#pragma unroll
    for (int q = 0; q < Q_N; ++q) {
        s16x8 bfrag = *(const s16x8*)(bB + q * 8);
        s16x8 a = *(const s16x8*)(aW + q * qs);
        f32x4 d = __builtin_amdgcn_mfma_f32_16x16x32_bf16(a, bfrag, cz, 0, 0, 0);
        const float sc = sp[q];
#pragma unroll
        for (int r = 0; r < 4; ++r) {
            float c0 = __builtin_amdgcn_cosf(d[r]);          // revolutions
            acc[r] = fmaf(sc, __builtin_amdgcn_rcpf(fmaf(-C2_C, c0, D_C)), acc[r]);
        }
    }

    // ---- store: pk = wv*16 + lh*4 + r, col = w0 + ll ----
    const int col = w0 + ll;
#pragma unroll
    for (int r = 0; r < 4; ++r) {
        const int pk = wv * 16 + lh * 4 + r;
        out[(b * 64 + pk) * (HW * HW) + row * HW + col] = acc[r];
    }
}

extern "C" void kernel_launch(void* const* d_in, const int* in_sizes, int n_in,
                              void* d_out, int out_size, void* d_ws, size_t ws_size,
                              hipStream_t stream) {
    const float* x      = (const float*)d_in[0];
    const float* weight = (const float*)d_in[1];
    const float* mos    = (const float*)d_in[2];
    float* out = (float*)d_out;
    unsigned char* ws = (unsigned char*)d_ws;

    hipLaunchKernelGGL(morr_pre, dim3(513), dim3(512), 0, stream, x, weight, mos, ws);
    // 8 images x 64 rows x 4 quarter-rows
    hipLaunchKernelGGL(morr_conv_kernel, dim3(2048), dim3(256), 0, stream, ws, out);
}